// Round 1
// baseline (240.677 us; speedup 1.0000x reference)
//
#include <hip/hip_runtime.h>

// Problem constants (from setup_inputs): B=4, N=32, R=64, H=480, W=640, fp32.
#define BDIM 4
#define NOBJ 32
#define HH 480
#define WW 640
#define RREL 64
#define HW (HH * WW)        // 307200
#define HW4 (HW / 4)        // 76800 float4 per (b,n) plane
#define CH 16               // chunks per (b,n) plane
#define CHUNK4 (HW4 / CH)   // 4800 float4 per chunk (exact)
#define BN (BDIM * NOBJ)    // 128
#define BR (BDIM * RREL)    // 256

// Kernel 1: per-(b,n) masked-depth sum + pixel count.
// grid = BN*CH blocks, 256 threads. Coalesced float4 streaming; depth plane is
// reused across the 32 masks of a batch -> L2/L3 resident. One atomicAdd pair
// per block into d_ws accumulators (zeroed by hipMemsetAsync beforehand).
__global__ __launch_bounds__(256) void rdl_mask_stats(
    const float* __restrict__ depth, const float* __restrict__ masks,
    float* __restrict__ sumd, unsigned int* __restrict__ cnt)
{
    const int blk = blockIdx.x;
    const int c   = blk & (CH - 1);
    const int bn  = blk / CH;
    const int b   = bn / NOBJ;

    const float4* __restrict__ mp =
        (const float4*)masks + (size_t)bn * HW4 + (size_t)c * CHUNK4;
    const float4* __restrict__ dp =
        (const float4*)depth + (size_t)b * HW4 + (size_t)c * CHUNK4;

    float s = 0.0f;
    unsigned int k = 0;
    for (int i = threadIdx.x; i < CHUNK4; i += 256) {
        const float4 m = mp[i];
        const float4 d = dp[i];
        if (m.x > 0.5f) { s += d.x; ++k; }
        if (m.y > 0.5f) { s += d.y; ++k; }
        if (m.z > 0.5f) { s += d.z; ++k; }
        if (m.w > 0.5f) { s += d.w; ++k; }
    }

    // wave(64)-level shuffle reduction
    for (int off = 32; off > 0; off >>= 1) {
        s += __shfl_down(s, off, 64);
        k += __shfl_down(k, off, 64);
    }
    __shared__ float        ls[4];
    __shared__ unsigned int lk[4];
    const int lane = threadIdx.x & 63;
    const int wave = threadIdx.x >> 6;
    if (lane == 0) { ls[wave] = s; lk[wave] = k; }
    __syncthreads();
    if (threadIdx.x == 0) {
        const float        st = ls[0] + ls[1] + ls[2] + ls[3];
        const unsigned int kt = lk[0] + lk[1] + lk[2] + lk[3];
        atomicAdd(&sumd[bn], st);
        atomicAdd(&cnt[bn], kt);
    }
}

// Kernel 2: one block. Compute d_obj/valid (128 entries), then one relation
// per thread (BR == 256 == blockDim), reduce, write the guarded mean.
__global__ __launch_bounds__(256) void rdl_loss(
    const float* __restrict__ sumd, const unsigned int* __restrict__ cnt,
    const int* __restrict__ subj, const int* __restrict__ obj,
    const int* __restrict__ rel, const float* __restrict__ conf,
    float* __restrict__ out)
{
    __shared__ float dobj[BN];
    __shared__ int   vobj[BN];
    const int t = threadIdx.x;
    if (t < BN) {
        const unsigned int c = cnt[t];
        dobj[t] = sumd[t] / fmaxf((float)c, 1.0f);
        vobj[t] = (c >= 20u) ? 1 : 0;
    }
    __syncthreads();

    float total;
    int   count;
    {
        const int b  = t / RREL;
        const int rt = rel[t];
        const int si = subj[t];
        const int oi = obj[t];
        const int ia = (rt == 1) ? oi : si;   // sA
        const int ib = (rt == 1) ? si : oi;   // sB
        const float dA = dobj[b * NOBJ + ia];
        const float dB = dobj[b * NOBJ + ib];
        const int   v  = vobj[b * NOBJ + ia] & vobj[b * NOBJ + ib];
        const float margin = (rt == 2) ? 0.3f : 0.1f;
        const float coeff  = (rt == 2) ? 1.5f : 1.0f;
        const float viol   = fmaxf(dA - dB + margin, 0.0f);
        total = coeff * conf[t] * (float)v * viol;
        count = v;
    }
    for (int off = 32; off > 0; off >>= 1) {
        total += __shfl_down(total, off, 64);
        count += __shfl_down(count, off, 64);
    }
    __shared__ float ts[4];
    __shared__ int   cs[4];
    const int lane = t & 63;
    const int wave = t >> 6;
    if (lane == 0) { ts[wave] = total; cs[wave] = count; }
    __syncthreads();
    if (t == 0) {
        const float tt = ts[0] + ts[1] + ts[2] + ts[3];
        const int   cc = cs[0] + cs[1] + cs[2] + cs[3];
        out[0] = (cc > 0) ? tt / fmaxf((float)cc, 1.0f) : 0.0f;
    }
}

extern "C" void kernel_launch(void* const* d_in, const int* in_sizes, int n_in,
                              void* d_out, int out_size, void* d_ws, size_t ws_size,
                              hipStream_t stream)
{
    const float* depth = (const float*)d_in[0];  // (B,1,H,W)
    const float* masks = (const float*)d_in[1];  // (B,N,H,W)
    const int*   subj  = (const int*)d_in[2];    // (B,R)
    const int*   obj   = (const int*)d_in[3];    // (B,R)
    const int*   rel   = (const int*)d_in[4];    // (B,R)
    const float* conf  = (const float*)d_in[5];  // (B,R)
    float*       out   = (float*)d_out;

    float*        sumd = (float*)d_ws;
    unsigned int* cnt  = (unsigned int*)((char*)d_ws + BN * sizeof(float));

    // Zero the accumulators (d_ws is poisoned 0xAA before every timed launch).
    hipMemsetAsync(d_ws, 0, BN * (sizeof(float) + sizeof(unsigned int)), stream);

    rdl_mask_stats<<<BN * CH, 256, 0, stream>>>(depth, masks, sumd, cnt);
    rdl_loss<<<1, 256, 0, stream>>>(sumd, cnt, subj, obj, rel, conf, out);
}

// Round 3
// 229.439 us; speedup vs baseline: 1.0490x; 1.0490x over previous
//
#include <hip/hip_runtime.h>

// Problem constants: B=4, N=32, R=64, H=480, W=640, fp32 throughout.
#define BDIM 4
#define NOBJ 32
#define RREL 64
#define HW 307200           // 480*640
#define HW4 (HW / 4)        // 76800 float4 per (b,n) plane
#define CH 16               // chunks per plane
#define CHUNK4 (HW4 / CH)   // 4800 float4 per chunk (exact)
#define BN (BDIM * NOBJ)    // 128
#define NBLK (BN * CH)      // 2048 blocks
#define BR (BDIM * RREL)    // 256 relations

// native clang vector type — required by __builtin_nontemporal_load
typedef float vfloat4 __attribute__((ext_vector_type(4)));

// Kernel 1: per-(b,n,chunk) masked-depth partial sum + pixel count.
// No atomics, no zero-init: each block writes its own d_ws slot.
// Block index is c-major so the 32 blocks sharing a depth chunk are
// dispatch-adjacent (depth stays L2-resident; masks streamed non-temporally).
__global__ __launch_bounds__(256) void rdl_mask_stats(
    const float* __restrict__ depth, const float* __restrict__ masks,
    float2* __restrict__ part)
{
    const int blk = blockIdx.x;
    const int c   = blk >> 7;          // 0..15
    const int bn  = blk & (BN - 1);    // 0..127
    const int b   = bn >> 5;           // 0..3

    const vfloat4* __restrict__ mp =
        (const vfloat4*)masks + (size_t)bn * HW4 + (size_t)c * CHUNK4;
    const vfloat4* __restrict__ dp =
        (const vfloat4*)depth + (size_t)b * HW4 + (size_t)c * CHUNK4;

    float s = 0.0f;
    float k = 0.0f;
    for (int i = threadIdx.x; i < CHUNK4; i += 256) {
        const vfloat4 m = __builtin_nontemporal_load(&mp[i]);  // no reuse
        const vfloat4 d = dp[i];                               // reused 32x: cache
        if (m.x > 0.5f) { s += d.x; k += 1.0f; }
        if (m.y > 0.5f) { s += d.y; k += 1.0f; }
        if (m.z > 0.5f) { s += d.z; k += 1.0f; }
        if (m.w > 0.5f) { s += d.w; k += 1.0f; }
    }

    // wave(64) shuffle reduction, then cross-wave via LDS
    for (int off = 32; off > 0; off >>= 1) {
        s += __shfl_down(s, off, 64);
        k += __shfl_down(k, off, 64);
    }
    __shared__ float ls[4], lk[4];
    const int lane = threadIdx.x & 63;
    const int wave = threadIdx.x >> 6;
    if (lane == 0) { ls[wave] = s; lk[wave] = k; }
    __syncthreads();
    if (threadIdx.x == 0) {
        part[blk] = make_float2(ls[0] + ls[1] + ls[2] + ls[3],
                                lk[0] + lk[1] + lk[2] + lk[3]);
    }
}

// Kernel 2: one block. Fold the 2048 partials into d_obj/valid (128 entries),
// then one relation per thread (BR == 256 == blockDim), reduce, guarded mean.
__global__ __launch_bounds__(256) void rdl_loss(
    const float2* __restrict__ part,
    const int* __restrict__ subj, const int* __restrict__ obj,
    const int* __restrict__ rel, const float* __restrict__ conf,
    float* __restrict__ out)
{
    __shared__ float dobj[BN];
    __shared__ int   vobj[BN];
    const int t = threadIdx.x;
    if (t < BN) {
        float s = 0.0f, k = 0.0f;
        #pragma unroll
        for (int c = 0; c < CH; ++c) {       // part[c*BN + t]: coalesced per c
            const float2 p = part[c * BN + t];
            s += p.x; k += p.y;
        }
        dobj[t] = s / fmaxf(k, 1.0f);
        vobj[t] = (k >= 20.0f) ? 1 : 0;
    }
    __syncthreads();

    float total;
    int   count;
    {
        const int b  = t / RREL;
        const int rt = rel[t];
        const int si = subj[t];
        const int oi = obj[t];
        const int ia = (rt == 1) ? oi : si;   // sA
        const int ib = (rt == 1) ? si : oi;   // sB
        const float dA = dobj[b * NOBJ + ia];
        const float dB = dobj[b * NOBJ + ib];
        const int   v  = vobj[b * NOBJ + ia] & vobj[b * NOBJ + ib];
        const float margin = (rt == 2) ? 0.3f : 0.1f;
        const float coeff  = (rt == 2) ? 1.5f : 1.0f;
        const float viol   = fmaxf(dA - dB + margin, 0.0f);
        total = coeff * conf[t] * (float)v * viol;
        count = v;
    }
    for (int off = 32; off > 0; off >>= 1) {
        total += __shfl_down(total, off, 64);
        count += __shfl_down(count, off, 64);
    }
    __shared__ float ts[4];
    __shared__ int   cs[4];
    const int lane = t & 63;
    const int wave = t >> 6;
    if (lane == 0) { ts[wave] = total; cs[wave] = count; }
    __syncthreads();
    if (t == 0) {
        const float tt = ts[0] + ts[1] + ts[2] + ts[3];
        const int   cc = cs[0] + cs[1] + cs[2] + cs[3];
        out[0] = (cc > 0) ? tt / fmaxf((float)cc, 1.0f) : 0.0f;
    }
}

extern "C" void kernel_launch(void* const* d_in, const int* in_sizes, int n_in,
                              void* d_out, int out_size, void* d_ws, size_t ws_size,
                              hipStream_t stream)
{
    const float* depth = (const float*)d_in[0];  // (B,1,H,W)
    const float* masks = (const float*)d_in[1];  // (B,N,H,W)
    const int*   subj  = (const int*)d_in[2];    // (B,R)
    const int*   obj   = (const int*)d_in[3];    // (B,R)
    const int*   rel   = (const int*)d_in[4];    // (B,R)
    const float* conf  = (const float*)d_in[5];  // (B,R)
    float*       out   = (float*)d_out;

    float2* part = (float2*)d_ws;                // NBLK float2 partials

    rdl_mask_stats<<<NBLK, 256, 0, stream>>>(depth, masks, part);
    rdl_loss<<<1, 256, 0, stream>>>(part, subj, obj, rel, conf, out);
}